// Round 1
// baseline (592.419 us; speedup 1.0000x reference)
//
#include <hip/hip_runtime.h>
#include <math.h>

#define K_PROTO 65536
#define NV 5              // student views used per chunk
#define SVIEWS 6          // n_views+1 student rows per chunk
#define TS_INV 10.0f      // 1 / t_student (0.1)
#define TT_INV 25.0f      // 1 / t_teacher (0.04)
#define BLOCK 1024
#define NWAVES (BLOCK / 64)

// One block per chunk c. Streams vt[2c..2c+1], vs[6c..6c+4], center once,
// computing teacher softmax normalizers, student LSEs, and the 10 exp-weighted
// dot products D[i][j] = sum_k exp(x_t[i,k]-m_i) * xs[j,k] in a single pass
// with online-max rescaling (amortized over 4 columns per iteration).
__global__ __launch_bounds__(BLOCK) void dino_loss_kernel(
    const float* __restrict__ vs,
    const float* __restrict__ vt,
    const float* __restrict__ center,
    float* __restrict__ out,
    int n, float inv_count)
{
    const int c   = blockIdx.x;
    const int tid = threadIdx.x;

    const float* __restrict__ t0 = vt + (size_t)(2 * c + 0) * K_PROTO;
    const float* __restrict__ t1 = vt + (size_t)(2 * c + 1) * K_PROTO;
    const float* __restrict__ s0 = vs + (size_t)(SVIEWS * c + 0) * K_PROTO;
    const float* __restrict__ s1 = vs + (size_t)(SVIEWS * c + 1) * K_PROTO;
    const float* __restrict__ s2 = vs + (size_t)(SVIEWS * c + 2) * K_PROTO;
    const float* __restrict__ s3 = vs + (size_t)(SVIEWS * c + 3) * K_PROTO;
    const float* __restrict__ s4 = vs + (size_t)(SVIEWS * c + 4) * K_PROTO;
    const float* srow[NV] = {s0, s1, s2, s3, s4};

    // online-softmax state
    float tm[2] = {-INFINITY, -INFINITY};   // teacher running max
    float tZ[2] = {0.f, 0.f};               // teacher running sumexp
    float D[2][NV];                         // exp-weighted dots
    float sm[NV], sZ[NV];                   // student running max / sumexp
#pragma unroll
    for (int i = 0; i < 2; ++i)
#pragma unroll
        for (int j = 0; j < NV; ++j) D[i][j] = 0.f;
#pragma unroll
    for (int j = 0; j < NV; ++j) { sm[j] = -INFINITY; sZ[j] = 0.f; }

    for (int k0 = tid * 4; k0 < K_PROTO; k0 += BLOCK * 4) {
        const float4 c4  = *(const float4*)(center + k0);
        const float4 t0v = *(const float4*)(t0 + k0);
        const float4 t1v = *(const float4*)(t1 + k0);
        float4 sv[NV];
#pragma unroll
        for (int j = 0; j < NV; ++j) sv[j] = *(const float4*)(srow[j] + k0);

        // ---- students: xs = vs*10 + 1e-20, online LSE (rescale amortized /4)
        float xs[NV][4];
#pragma unroll
        for (int j = 0; j < NV; ++j) {
            xs[j][0] = fmaf(sv[j].x, TS_INV, 1e-20f);
            xs[j][1] = fmaf(sv[j].y, TS_INV, 1e-20f);
            xs[j][2] = fmaf(sv[j].z, TS_INV, 1e-20f);
            xs[j][3] = fmaf(sv[j].w, TS_INV, 1e-20f);
            float m4 = fmaxf(fmaxf(xs[j][0], xs[j][1]), fmaxf(xs[j][2], xs[j][3]));
            float mn = fmaxf(sm[j], m4);
            float r  = __expf(sm[j] - mn);
            float p0 = __expf(xs[j][0] - mn);
            float p1 = __expf(xs[j][1] - mn);
            float p2 = __expf(xs[j][2] - mn);
            float p3 = __expf(xs[j][3] - mn);
            sZ[j] = fmaf(sZ[j], r, (p0 + p1) + (p2 + p3));
            sm[j] = mn;
        }

        // ---- teachers: x = (vt-center)*25, online softmax + dot accumulation
#pragma unroll
        for (int i = 0; i < 2; ++i) {
            const float4 tv = i ? t1v : t0v;
            float x0 = (tv.x - c4.x) * TT_INV;
            float x1 = (tv.y - c4.y) * TT_INV;
            float x2 = (tv.z - c4.z) * TT_INV;
            float x3 = (tv.w - c4.w) * TT_INV;
            float m4 = fmaxf(fmaxf(x0, x1), fmaxf(x2, x3));
            float mn = fmaxf(tm[i], m4);
            float r  = __expf(tm[i] - mn);
            float p0 = __expf(x0 - mn);
            float p1 = __expf(x1 - mn);
            float p2 = __expf(x2 - mn);
            float p3 = __expf(x3 - mn);
            tZ[i] = fmaf(tZ[i], r, (p0 + p1) + (p2 + p3));
#pragma unroll
            for (int j = 0; j < NV; ++j) {
                float acc = fmaf(p0, xs[j][0],
                            fmaf(p1, xs[j][1],
                            fmaf(p2, xs[j][2], p3 * xs[j][3])));
                D[i][j] = fmaf(D[i][j], r, acc);
            }
            tm[i] = mn;
        }
    }

    // ---- wave-level (64-lane) online-softmax merge via shfl_xor
#pragma unroll
    for (int off = 32; off >= 1; off >>= 1) {
#pragma unroll
        for (int i = 0; i < 2; ++i) {
            float om = __shfl_xor(tm[i], off);
            float oZ = __shfl_xor(tZ[i], off);
            float oD[NV];
#pragma unroll
            for (int j = 0; j < NV; ++j) oD[j] = __shfl_xor(D[i][j], off);
            float mn = fmaxf(tm[i], om);
            float a  = __expf(tm[i] - mn);
            float b  = __expf(om - mn);
            tZ[i] = tZ[i] * a + oZ * b;
#pragma unroll
            for (int j = 0; j < NV; ++j) D[i][j] = D[i][j] * a + oD[j] * b;
            tm[i] = mn;
        }
#pragma unroll
        for (int j = 0; j < NV; ++j) {
            float om = __shfl_xor(sm[j], off);
            float oZ = __shfl_xor(sZ[j], off);
            float mn = fmaxf(sm[j], om);
            sZ[j] = sZ[j] * __expf(sm[j] - mn) + oZ * __expf(om - mn);
            sm[j] = mn;
        }
    }

    // ---- cross-wave merge through LDS (lane 0 of each wave -> 24 floats)
    __shared__ float red[NWAVES][24];
    const int wave = tid >> 6;
    const int lane = tid & 63;
    if (lane == 0) {
        float* r = red[wave];
        r[0] = tm[0]; r[1] = tm[1]; r[2] = tZ[0]; r[3] = tZ[1];
#pragma unroll
        for (int i = 0; i < 2; ++i)
#pragma unroll
            for (int j = 0; j < NV; ++j) r[4 + i * NV + j] = D[i][j];
#pragma unroll
        for (int j = 0; j < NV; ++j) { r[14 + j] = sm[j]; r[19 + j] = sZ[j]; }
    }
    __syncthreads();

    if (tid == 0) {
        float gm[2], gZ[2], gD[2][NV], gsm[NV], gsZ[NV];
        gm[0] = red[0][0]; gm[1] = red[0][1]; gZ[0] = red[0][2]; gZ[1] = red[0][3];
#pragma unroll
        for (int i = 0; i < 2; ++i)
#pragma unroll
            for (int j = 0; j < NV; ++j) gD[i][j] = red[0][4 + i * NV + j];
#pragma unroll
        for (int j = 0; j < NV; ++j) { gsm[j] = red[0][14 + j]; gsZ[j] = red[0][19 + j]; }

        for (int w = 1; w < NWAVES; ++w) {
            const float* r = red[w];
#pragma unroll
            for (int i = 0; i < 2; ++i) {
                float om = r[i], oZ = r[2 + i];
                float mn = fmaxf(gm[i], om);
                float a = __expf(gm[i] - mn), b = __expf(om - mn);
                gZ[i] = gZ[i] * a + oZ * b;
#pragma unroll
                for (int j = 0; j < NV; ++j)
                    gD[i][j] = gD[i][j] * a + r[4 + i * NV + j] * b;
                gm[i] = mn;
            }
#pragma unroll
            for (int j = 0; j < NV; ++j) {
                float om = r[14 + j], oZ = r[19 + j];
                float mn = fmaxf(gsm[j], om);
                gsZ[j] = gsZ[j] * __expf(gsm[j] - mn) + oZ * __expf(om - mn);
                gsm[j] = mn;
            }
        }

        // loss contribution: sum_{i,j} (lse_j - D[i][j]/Z_i)
        float sum = 0.f;
#pragma unroll
        for (int j = 0; j < NV; ++j) {
            float lse = gsm[j] + __logf(gsZ[j]);
#pragma unroll
            for (int i = 0; i < 2; ++i)
                sum += lse - gD[i][j] / gZ[i];
        }
        atomicAdd(out, sum * inv_count);
    }
}

extern "C" void kernel_launch(void* const* d_in, const int* in_sizes, int n_in,
                              void* d_out, int out_size, void* d_ws, size_t ws_size,
                              hipStream_t stream) {
    const float* vs     = (const float*)d_in[0];
    const float* vt     = (const float*)d_in[1];
    const float* center = (const float*)d_in[2];
    float* out = (float*)d_out;

    const int S = in_sizes[0] / K_PROTO;   // 1536
    const int T = in_sizes[1] / K_PROTO;   // 512
    int n = S / SVIEWS;
    if (T / 2 < n) n = T / 2;              // 256

    hipMemsetAsync(out, 0, sizeof(float), stream);
    if (n > 0) {
        const float inv_count = 1.0f / (float)(n * 2 * NV);
        dino_loss_kernel<<<n, BLOCK, 0, stream>>>(vs, vt, center, out, n, inv_count);
    }
}

// Round 3
// 564.099 us; speedup vs baseline: 1.0502x; 1.0502x over previous
//
#include <hip/hip_runtime.h>
#include <math.h>

#define K_PROTO 65536
#define NV 5              // student views used per chunk
#define SVIEWS 6          // n_views+1 student rows per chunk
#define TS_INV 10.0f      // 1 / t_student (0.1)
#define TT_INV 25.0f      // 1 / t_teacher (0.04)
#define NSLICE 16         // K-slices per chunk (one wave each)
#define SLICE (K_PROTO / NSLICE)          // 4096 columns per wave
#define BLOCK 256
#define WPB (BLOCK / 64)                  // 4 waves per block
#define ITERS (SLICE / (64 * 4))          // 16 iterations of float4 per lane
#define PSTRIDE 24                        // floats per wave partial

typedef float floatx4 __attribute__((ext_vector_type(4)));

__device__ __forceinline__ floatx4 ntload4(const float* p) {
    return __builtin_nontemporal_load((const floatx4*)p);
}
__device__ __forceinline__ floatx4 ld4(const float* p) {
    return *(const floatx4*)p;
}

// Streaming kernel: one wave per (chunk, K-slice). No LDS, no barriers.
// Each wave computes partial online-softmax state over its 4096 columns:
// teacher (max m, sumexp Z), student (max, sumexp), and exp-weighted dots
// D[i][j] = sum_k exp(xt[i,k]-m_i)*xs[j,k], then writes 24 floats to ws.
__global__ __launch_bounds__(BLOCK) void dino_partial(
    const float* __restrict__ vs,
    const float* __restrict__ vt,
    const float* __restrict__ center,
    float* __restrict__ ws)
{
    const int w    = blockIdx.x * WPB + (threadIdx.x >> 6);
    const int lane = threadIdx.x & 63;
    const int c    = w >> 4;              // chunk index
    const int s    = w & (NSLICE - 1);    // K-slice index
    const int kb   = s * SLICE + lane * 4;

    // row base pointers (already offset to this wave's slice + lane)
    const float* rp[8];
    rp[0] = center + kb;
    rp[1] = vt + (size_t)(2 * c + 0) * K_PROTO + kb;
    rp[2] = vt + (size_t)(2 * c + 1) * K_PROTO + kb;
#pragma unroll
    for (int j = 0; j < NV; ++j)
        rp[3 + j] = vs + (size_t)(SVIEWS * c + j) * K_PROTO + kb;

    // online-softmax state
    float tm[2] = {-INFINITY, -INFINITY};
    float tZ[2] = {0.f, 0.f};
    float D[2][NV];
    float sm[NV], sZ[NV];
#pragma unroll
    for (int i = 0; i < 2; ++i)
#pragma unroll
        for (int j = 0; j < NV; ++j) D[i][j] = 0.f;
#pragma unroll
    for (int j = 0; j < NV; ++j) { sm[j] = -INFINITY; sZ[j] = 0.f; }

    // prime the double buffer
    floatx4 cur[8];
    cur[0] = ld4(rp[0]);                  // center: normal load (L2-reused)
#pragma unroll
    for (int r = 1; r < 8; ++r) cur[r] = ntload4(rp[r]);

    for (int it = 0; it < ITERS; ++it) {
        floatx4 nxt[8];
        const bool more = (it + 1 < ITERS);
        if (more) {
            const int off = (it + 1) * 64 * 4;
            nxt[0] = ld4(rp[0] + off);
#pragma unroll
            for (int r = 1; r < 8; ++r) nxt[r] = ntload4(rp[r] + off);
        }

        // ---- students: xs = vs*10 + 1e-20, online LSE
        float xs[NV][4];
#pragma unroll
        for (int j = 0; j < NV; ++j) {
            const floatx4 sv = cur[3 + j];
            xs[j][0] = fmaf(sv.x, TS_INV, 1e-20f);
            xs[j][1] = fmaf(sv.y, TS_INV, 1e-20f);
            xs[j][2] = fmaf(sv.z, TS_INV, 1e-20f);
            xs[j][3] = fmaf(sv.w, TS_INV, 1e-20f);
            float m4 = fmaxf(fmaxf(xs[j][0], xs[j][1]), fmaxf(xs[j][2], xs[j][3]));
            float mn = fmaxf(sm[j], m4);
            float r  = __expf(sm[j] - mn);
            float p0 = __expf(xs[j][0] - mn);
            float p1 = __expf(xs[j][1] - mn);
            float p2 = __expf(xs[j][2] - mn);
            float p3 = __expf(xs[j][3] - mn);
            sZ[j] = fmaf(sZ[j], r, (p0 + p1) + (p2 + p3));
            sm[j] = mn;
        }

        // ---- teachers: x = (vt-center)*25, online softmax + weighted dots
        const floatx4 c4 = cur[0];
#pragma unroll
        for (int i = 0; i < 2; ++i) {
            const floatx4 tv = cur[1 + i];
            float x0 = (tv.x - c4.x) * TT_INV;
            float x1 = (tv.y - c4.y) * TT_INV;
            float x2 = (tv.z - c4.z) * TT_INV;
            float x3 = (tv.w - c4.w) * TT_INV;
            float m4 = fmaxf(fmaxf(x0, x1), fmaxf(x2, x3));
            float mn = fmaxf(tm[i], m4);
            float r  = __expf(tm[i] - mn);
            float p0 = __expf(x0 - mn);
            float p1 = __expf(x1 - mn);
            float p2 = __expf(x2 - mn);
            float p3 = __expf(x3 - mn);
            tZ[i] = fmaf(tZ[i], r, (p0 + p1) + (p2 + p3));
#pragma unroll
            for (int j = 0; j < NV; ++j) {
                float acc = fmaf(p0, xs[j][0],
                            fmaf(p1, xs[j][1],
                            fmaf(p2, xs[j][2], p3 * xs[j][3])));
                D[i][j] = fmaf(D[i][j], r, acc);
            }
            tm[i] = mn;
        }

        if (more) {
#pragma unroll
            for (int r = 0; r < 8; ++r) cur[r] = nxt[r];
        }
    }

    // ---- 64-lane butterfly merge (all lanes end with the merged state)
#pragma unroll
    for (int off = 32; off >= 1; off >>= 1) {
#pragma unroll
        for (int i = 0; i < 2; ++i) {
            float om = __shfl_xor(tm[i], off);
            float oZ = __shfl_xor(tZ[i], off);
            float oD[NV];
#pragma unroll
            for (int j = 0; j < NV; ++j) oD[j] = __shfl_xor(D[i][j], off);
            float mn = fmaxf(tm[i], om);
            float a  = __expf(tm[i] - mn);
            float b  = __expf(om - mn);
            tZ[i] = tZ[i] * a + oZ * b;
#pragma unroll
            for (int j = 0; j < NV; ++j) D[i][j] = D[i][j] * a + oD[j] * b;
            tm[i] = mn;
        }
#pragma unroll
        for (int j = 0; j < NV; ++j) {
            float om = __shfl_xor(sm[j], off);
            float oZ = __shfl_xor(sZ[j], off);
            float mn = fmaxf(sm[j], om);
            sZ[j] = sZ[j] * __expf(sm[j] - mn) + oZ * __expf(om - mn);
            sm[j] = mn;
        }
    }

    if (lane == 0) {
        float* p = ws + (size_t)w * PSTRIDE;
        p[0] = tm[0]; p[1] = tm[1]; p[2] = tZ[0]; p[3] = tZ[1];
#pragma unroll
        for (int i = 0; i < 2; ++i)
#pragma unroll
            for (int j = 0; j < NV; ++j) p[4 + i * NV + j] = D[i][j];
#pragma unroll
        for (int j = 0; j < NV; ++j) { p[14 + j] = sm[j]; p[19 + j] = sZ[j]; }
    }
}

// Single-block finalize: merge NSLICE partials per chunk, sum, write out[0].
__global__ __launch_bounds__(256) void dino_finalize(
    const float* __restrict__ ws, float* __restrict__ out,
    int n, float inv_count)
{
    const int t = threadIdx.x;
    float local = 0.f;

    for (int c = t; c < n; c += 256) {
        const float* p = ws + (size_t)c * NSLICE * PSTRIDE;
        float gm[2], gZ[2], gD[2][NV], gsm[NV], gsZ[NV];
        gm[0] = p[0]; gm[1] = p[1]; gZ[0] = p[2]; gZ[1] = p[3];
#pragma unroll
        for (int i = 0; i < 2; ++i)
#pragma unroll
            for (int j = 0; j < NV; ++j) gD[i][j] = p[4 + i * NV + j];
#pragma unroll
        for (int j = 0; j < NV; ++j) { gsm[j] = p[14 + j]; gsZ[j] = p[19 + j]; }

        for (int s2 = 1; s2 < NSLICE; ++s2) {
            const float* q = p + s2 * PSTRIDE;
#pragma unroll
            for (int i = 0; i < 2; ++i) {
                float om = q[i], oZ = q[2 + i];
                float mn = fmaxf(gm[i], om);
                float a = __expf(gm[i] - mn), b = __expf(om - mn);
                gZ[i] = gZ[i] * a + oZ * b;
#pragma unroll
                for (int j = 0; j < NV; ++j)
                    gD[i][j] = gD[i][j] * a + q[4 + i * NV + j] * b;
                gm[i] = mn;
            }
#pragma unroll
            for (int j = 0; j < NV; ++j) {
                float om = q[14 + j], oZ = q[19 + j];
                float mn = fmaxf(gsm[j], om);
                gsZ[j] = gsZ[j] * __expf(gsm[j] - mn) + oZ * __expf(om - mn);
                gsm[j] = mn;
            }
        }

        float sum = 0.f;
#pragma unroll
        for (int j = 0; j < NV; ++j) {
            float lse = gsm[j] + __logf(gsZ[j]);
#pragma unroll
            for (int i = 0; i < 2; ++i)
                sum += lse - gD[i][j] / gZ[i];
        }
        local += sum;
    }

    // block-wide sum (4 waves)
#pragma unroll
    for (int off = 32; off >= 1; off >>= 1) local += __shfl_xor(local, off);
    __shared__ float red[4];
    if ((t & 63) == 0) red[t >> 6] = local;
    __syncthreads();
    if (t == 0) out[0] = (red[0] + red[1] + red[2] + red[3]) * inv_count;
}

extern "C" void kernel_launch(void* const* d_in, const int* in_sizes, int n_in,
                              void* d_out, int out_size, void* d_ws, size_t ws_size,
                              hipStream_t stream) {
    const float* vs     = (const float*)d_in[0];
    const float* vt     = (const float*)d_in[1];
    const float* center = (const float*)d_in[2];
    float* out = (float*)d_out;
    float* ws  = (float*)d_ws;

    const int S = in_sizes[0] / K_PROTO;   // 1536
    const int T = in_sizes[1] / K_PROTO;   // 512
    int n = S / SVIEWS;
    if (T / 2 < n) n = T / 2;              // 256

    if (n > 0) {
        const int nblocks = n * NSLICE / WPB;   // 1024
        dino_partial<<<nblocks, BLOCK, 0, stream>>>(vs, vt, center, ws);
        dino_finalize<<<1, 256, 0, stream>>>(ws, out, n, 1.0f / (float)(n * 2 * NV));
    }
}